// Round 8
// baseline (259.554 us; speedup 1.0000x reference)
//
#include <hip/hip_runtime.h>
#include <hip/hip_bf16.h>

typedef __attribute__((ext_vector_type(8))) short short8;
typedef __attribute__((ext_vector_type(16))) float f32x16;
typedef __attribute__((ext_vector_type(4))) float f32x4;

#define LL 16
#define NP3 23
#define NE 10
#define NC 128
#define KI 24            // fused K stride per i: 23 U3 slots + 1 U2/zero slot
#define NSKH 12          // K-steps per block (K split in halves of 192)
#define MB 128           // rows per block (= one b)
#define THREADS 512
#define BHALF 98304      // bytes of one K-half of B: 96 frags * 64 lanes * 16 B

static __device__ __forceinline__ short f2bs(float f) {
    __hip_bfloat16 h = __float2bfloat16(f);
    short s;
    __builtin_memcpy(&s, &h, 2);
    return s;
}

// ---- kernel 1: pack U3/U2 -> fragment-major bf16 B, K-half-major ----
// g = kh*96 + t*12 + s12 ; lane: col = t*32+(lane&31), K = (kh*12+s12)*16+(lane>>5)*8+j
// B[n][K], K = i*24+kk : kk<23 ? U3[n][i][kk] : (i<4 ? U2[n][i] : 0)
__global__ void build_B(const float* __restrict__ U3, const float* __restrict__ U2,
                        __hip_bfloat16* __restrict__ Bf) {
    int g   = blockIdx.x;            // 0..191
    int kh  = g / 96, r96 = g % 96;
    int t   = r96 / NSKH, s12 = r96 % NSKH;
    int s   = kh * NSKH + s12;
    int lane = threadIdx.x;
    int col  = t * 32 + (lane & 31);
    int hi   = lane >> 5;
    short8 v;
#pragma unroll
    for (int j = 0; j < 8; ++j) {
        int K = s * 16 + hi * 8 + j;
        int i = K / KI, kk = K - i * KI;
        float f;
        if (kk < NP3)    f = U3[((size_t)col * LL + i) * NP3 + kk];
        else if (i < 4)  f = U2[col * 4 + i];
        else             f = 0.f;
        v[j] = f2bs(f);
    }
    *reinterpret_cast<short8*>(Bf + ((size_t)g * 64 + lane) * 8) = v;
}

// A-build for a compile-time K-base (kh*192 + hi*8): all indices constant-fold
#define BUILD_A(DST, KB)                                                      \
    _Pragma("unroll")                                                         \
    for (int s = 0; s < NSKH; ++s) {                                          \
        short8 av;                                                            \
        _Pragma("unroll")                                                     \
        for (int j = 0; j < 8; ++j) {                                         \
            const int K  = (KB) + s * 16 + j;                                 \
            const int i  = K / KI;                                            \
            const int kk = K - i * KI;                                        \
            float f = (kk < NP3) ? xr[i] * wr[kk]                             \
                                 : ((i < 4) ? w2r[i] : 0.f);                  \
            av[j] = f2bs(f);                                                  \
        }                                                                     \
        DST[s] = av;                                                          \
    }

// ---- kernel 2: fused contraction; B-half resident in LDS, no main-loop barriers ----
__global__ __launch_bounds__(THREADS, 2)
void contract_k(const float* __restrict__ x, const float* __restrict__ y,
                const float* __restrict__ W3, const float* __restrict__ W2,
                const float* __restrict__ W1, const float* __restrict__ U1,
                const __hip_bfloat16* __restrict__ Bf, float* __restrict__ out) {
    __shared__ __align__(16) char Bs[BHALF];   // 96 KB, loaded once, read-only after
    __shared__ float xs[MB][20];               // 80 B stride: b128-aligned, 4-way worst
    __shared__ float wys[MB][36];              // 144 B stride: b128-aligned, 4-way worst
    __shared__ float part[MB][4];

    const int tid    = threadIdx.x;
    const int rowblk = blockIdx.x >> 1;
    const int kh     = blockIdx.x & 1;         // this block's K-half
    const int m0     = rowblk * MB;
    const int b      = rowblk;                 // MB == NC -> one b per row-block

    // issue the one-time B-half load (12 x 16 B per thread); lands under Wy phase
    f32x4 st[12];
    {
        const f32x4* p = reinterpret_cast<const f32x4*>(Bf) + (size_t)kh * (BHALF / 16) + tid;
#pragma unroll
        for (int j = 0; j < 12; ++j) st[j] = p[j * THREADS];
    }

    // stage x rows (coalesced)
    for (int idx = tid; idx < MB * LL; idx += THREADS)
        xs[idx >> 4][idx & 15] = x[(size_t)m0 * LL + idx];
    __syncthreads();                 // xs visible (du term reads it)

    // Wy = y.W, coalesced over c (=r); plus du[r] = U1 . x[r]
    float yv[NE];
#pragma unroll
    for (int e = 0; e < NE; ++e) yv[e] = y[(size_t)b * NE + e];

    for (int u = tid; u < 29 * MB; u += THREADS) {
        int idx = u >> 7, r = u & (MB - 1);
        float s = 0.f;
        if (idx < NP3) {
#pragma unroll
            for (int e = 0; e < NE; ++e) s += yv[e] * W3[(e * NP3 + idx) * NC + r];
        } else if (idx < 27) {
#pragma unroll
            for (int e = 0; e < NE; ++e) s += yv[e] * W2[(e * 4 + (idx - NP3)) * NC + r];
        } else if (idx == 27) {
#pragma unroll
            for (int e = 0; e < NE; ++e) s += yv[e] * W1[e * NC + r];
        } else {
#pragma unroll
            for (int w = 0; w < LL; ++w) s += U1[w] * xs[r][w];
        }
        wys[r][idx] = s;
    }

    // commit B-half to LDS (vmcnt drained on st use automatically)
    {
        f32x4* q = reinterpret_cast<f32x4*>(Bs) + tid;
#pragma unroll
        for (int j = 0; j < 12; ++j) q[j * THREADS] = st[j];
    }
    __syncthreads();                 // wys + Bs visible; no more barriers until epilogue

    // wave geometry: wave = (rp row-pair, nh N-pair); 2 rowtiles x 2 N-tiles x 12 K-steps
    const int lane = tid & 63;
    const int wv   = tid >> 6;       // 0..7
    const int rp   = wv & 1;         // rowtiles {2rp, 2rp+1}
    const int nh   = wv >> 1;        // N-tiles {2nh, 2nh+1}
    const int l31  = lane & 31;
    const int hi   = lane >> 5;
    const int bsel = l31 >> 4;

    // build A fragments for both rowtiles (96 VGPR)
    short8 A2[2][NSKH];
#pragma unroll
    for (int rr = 0; rr < 2; ++rr) {
        const int arow = (rp * 2 + rr) * 32 + l31;
        float xr[LL], wr[NP3], w2r[4];
#pragma unroll
        for (int i = 0; i < LL; ++i) xr[i] = xs[arow][i];
#pragma unroll
        for (int k = 0; k < NP3; ++k) wr[k] = wys[arow][k];
#pragma unroll
        for (int i = 0; i < 4; ++i) w2r[i] = wys[arow][NP3 + i];
        if (kh == 0) {
            if (hi == 0) { BUILD_A(A2[rr], 0) }   else { BUILD_A(A2[rr], 8) }
        } else {
            if (hi == 0) { BUILD_A(A2[rr], 192) } else { BUILD_A(A2[rr], 200) }
        }
    }

    // xx[rr][q] = x[row(rr,q)][x-col]  (x-col == lane&15 for every tile)
    float xx[2][16];
#pragma unroll
    for (int rr = 0; rr < 2; ++rr)
#pragma unroll
        for (int q = 0; q < 16; ++q) {
            int rowq = ((rp * 2 + rr) << 5) + (q & 3) + ((q >> 2) << 3) + (hi << 2);
            xx[rr][q] = xs[rowq][lane & 15];
        }

    float acc_out[2][16];
#pragma unroll
    for (int rr = 0; rr < 2; ++rr)
#pragma unroll
        for (int q = 0; q < 16; ++q) acc_out[rr][q] = 0.f;

    // main loop: pure LDS->MFMA, each B frag feeds both rowtiles
    const short8* BsV = reinterpret_cast<const short8*>(Bs);
#pragma unroll
    for (int tt = 0; tt < 2; ++tt) {
        const int t = nh * 2 + tt;
        f32x16 a0, a1;
#pragma unroll
        for (int q = 0; q < 16; ++q) { a0[q] = 0.f; a1[q] = 0.f; }
        __builtin_amdgcn_s_setprio(1);
#pragma unroll
        for (int s = 0; s < NSKH; ++s) {
            short8 bfrag = BsV[(t * NSKH + s) * 64 + lane];
            a0 = __builtin_amdgcn_mfma_f32_32x32x16_bf16(A2[0][s], bfrag, a0, 0, 0, 0);
            a1 = __builtin_amdgcn_mfma_f32_32x32x16_bf16(A2[1][s], bfrag, a1, 0, 0, 0);
        }
        __builtin_amdgcn_s_setprio(0);
        // fold tile t: col = t*32 + l31 ; w = 2t + bsel ; x = lane&15
#pragma unroll
        for (int q = 0; q < 16; ++q) {
            int r0 = ((rp * 2 + 0) << 5) + (q & 3) + ((q >> 2) << 3) + (hi << 2);
            int r1 = ((rp * 2 + 1) << 5) + (q & 3) + ((q >> 2) << 3) + (hi << 2);
            acc_out[0][q] += a0[q] * xx[0][q] * xs[r0][2 * t + bsel];
            acc_out[1][q] += a1[q] * xx[1][q] * xs[r1][2 * t + bsel];
        }
    }

    // butterfly over the 32-lane half (row depends on (q,hi) only), stash partials
#pragma unroll
    for (int rr = 0; rr < 2; ++rr)
#pragma unroll
        for (int q = 0; q < 16; ++q) {
            float v = acc_out[rr][q];
            v += __shfl_xor(v, 1);
            v += __shfl_xor(v, 2);
            v += __shfl_xor(v, 4);
            v += __shfl_xor(v, 8);
            v += __shfl_xor(v, 16);
            if (l31 == 0) {
                int rowq = ((rp * 2 + rr) << 5) + (q & 3) + ((q >> 2) << 3) + (hi << 2);
                part[rowq][nh] = v;
            }
        }
    __syncthreads();

    // combine 4 N-pair partials; U1 term from the kh==0 block; K-halves via atomicAdd
    if (tid < MB) {
        float v = part[tid][0] + part[tid][1] + part[tid][2] + part[tid][3];
        if (kh == 0) v += wys[tid][27] * wys[tid][28];
        atomicAdd(out + m0 + tid, v);
    }
}

extern "C" void kernel_launch(void* const* d_in, const int* in_sizes, int n_in,
                              void* d_out, int out_size, void* d_ws, size_t ws_size,
                              hipStream_t stream) {
    const float* x  = (const float*)d_in[0];
    const float* y  = (const float*)d_in[1];
    const float* U3 = (const float*)d_in[2];
    const float* U2 = (const float*)d_in[3];
    const float* U1 = (const float*)d_in[4];
    const float* W3 = (const float*)d_in[5];
    const float* W2 = (const float*)d_in[6];
    const float* W1 = (const float*)d_in[7];
    __hip_bfloat16* Bf = (__hip_bfloat16*)d_ws;   // 192 frags * 64 lanes * 8 bf16 * 2B = 196608 B

    hipMemsetAsync(d_out, 0, (size_t)out_size * sizeof(float), stream);
    build_B<<<192, 64, 0, stream>>>(U3, U2, Bf);
    contract_k<<<4096, THREADS, 0, stream>>>(x, y, W3, W2, W1, U1, Bf, (float*)d_out);
}